// Round 2
// baseline (1503.098 us; speedup 1.0000x reference)
//
#include <hip/hip_runtime.h>
#include <hip/hip_bf16.h>
#include <math.h>

// Problem dims
#define B_     1024
#define T_     8
#define DIMM   512          // dim
#define DM1    511          // dim-1
#define NC     8192         // NUM_CODES
#define M_     8192         // B*T
#define NNZ_   65536
#define NEV    16384
#define K1_    768
#define N1_    4088         // T*(dim-1)

// Workspace layout (floats):
//   [0..7]   scalars: 0=num_masked 1=base 2=corr 3=evsum
//   [8 .. 8+8192)  row_sum
//   [8+8192 .. )   full_a [M_][DIMM]
#define WS_ROWSUM 8
#define WS_FULLA  (8 + 8192)

// ---------------------------------------------------------------------------
// GEMM1: binned = features @ final_W + final_b, scattered into full_a layout
// C[m][n], m in [0,1024), n in [0,4088); full_a[(m*8 + n/511)*512 + n%511]
// ---------------------------------------------------------------------------
__global__ __launch_bounds__(256) void gemm1_kernel(
    const float* __restrict__ A,    // features [1024][768]
    const float* __restrict__ W,    // final_W  [768][4088]
    const float* __restrict__ bias, // final_b  [4088]
    float* __restrict__ fa)         // full_a   [8192][512]
{
    __shared__ float As[16][132];
    __shared__ float Bs[16][132];
    const int bm = blockIdx.y * 128;
    const int bn = blockIdx.x * 128;
    const int t  = threadIdx.x;
    const int tx = t % 16, ty = t / 16;

    float acc[8][8];
#pragma unroll
    for (int i = 0; i < 8; i++)
#pragma unroll
        for (int j = 0; j < 8; j++) acc[i][j] = 0.f;

    for (int k0 = 0; k0 < K1_; k0 += 16) {
        // A tile 128x16 (row-major, K contiguous) -> As[k][m] transposed
#pragma unroll
        for (int rep = 0; rep < 2; rep++) {
            int row = t / 4 + rep * 64;
            int kk  = (t % 4) * 4;
            float4 v = *reinterpret_cast<const float4*>(&A[(size_t)(bm + row) * K1_ + k0 + kk]);
            As[kk + 0][row] = v.x; As[kk + 1][row] = v.y;
            As[kk + 2][row] = v.z; As[kk + 3][row] = v.w;
        }
        // B tile 16x128 (already [k][n]) -> Bs[k][n]
#pragma unroll
        for (int rep = 0; rep < 2; rep++) {
            int k  = t / 32 + rep * 8;
            int n  = (t % 32) * 4;
            int gn = bn + n;
            float4 v;
            if (gn + 3 < N1_) {
                v = *reinterpret_cast<const float4*>(&W[(size_t)(k0 + k) * N1_ + gn]);
            } else {
                v.x = (gn + 0 < N1_) ? W[(size_t)(k0 + k) * N1_ + gn + 0] : 0.f;
                v.y = (gn + 1 < N1_) ? W[(size_t)(k0 + k) * N1_ + gn + 1] : 0.f;
                v.z = (gn + 2 < N1_) ? W[(size_t)(k0 + k) * N1_ + gn + 2] : 0.f;
                v.w = 0.f;
            }
            *reinterpret_cast<float4*>(&Bs[k][n]) = v;
        }
        __syncthreads();
#pragma unroll
        for (int k = 0; k < 16; k++) {
            float a[8], b[8];
            *reinterpret_cast<float4*>(&a[0]) = *reinterpret_cast<const float4*>(&As[k][ty * 4]);
            *reinterpret_cast<float4*>(&a[4]) = *reinterpret_cast<const float4*>(&As[k][ty * 4 + 64]);
            *reinterpret_cast<float4*>(&b[0]) = *reinterpret_cast<const float4*>(&Bs[k][tx * 4]);
            *reinterpret_cast<float4*>(&b[4]) = *reinterpret_cast<const float4*>(&Bs[k][tx * 4 + 64]);
#pragma unroll
            for (int i = 0; i < 8; i++)
#pragma unroll
                for (int j = 0; j < 8; j++) acc[i][j] += a[i] * b[j];
        }
        __syncthreads();
    }

#pragma unroll
    for (int i = 0; i < 8; i++) {
        int m = bm + ty * 4 + (i & 3) + (i >> 2) * 64;   // batch row, 0..1023
#pragma unroll
        for (int j = 0; j < 8; j++) {
            int n = bn + tx * 4 + (j & 3) + (j >> 2) * 64;
            if (n < N1_) {
                int tt = n / DM1;
                int d  = n - tt * DM1;
                fa[(size_t)(m * T_ + tt) * DIMM + d] = acc[i][j] + bias[n];
            }
        }
    }
}

// full_a[:, 511] = 1.0
__global__ void fill_ones_kernel(float* __restrict__ fa)
{
    int i = blockIdx.x * blockDim.x + threadIdx.x;
    if (i < M_) fa[(size_t)i * DIMM + DM1] = 1.0f;
}

// ---------------------------------------------------------------------------
// GEMM2: dot = full_a @ tcw^T ; logits = exp2(dot) -> d_out+1 ; row_sum atomics
// A = full_a [8192][512], B = code_weight [8192][511] (+ bias col 511)
// ---------------------------------------------------------------------------
__global__ __launch_bounds__(256) void gemm2_kernel(
    const float* __restrict__ fa,   // [8192][512]
    const float* __restrict__ cw,   // [8192][511]
    const float* __restrict__ cwb,  // [8192]
    float* __restrict__ logits,     // d_out + 1, [8192][8192]
    float* __restrict__ row_sum)    // [8192]
{
    __shared__ float As[16][132];
    __shared__ float Bs[16][132];
    const int bm = blockIdx.y * 128;
    const int bn = blockIdx.x * 128;
    const int t  = threadIdx.x;
    const int tx = t % 16, ty = t / 16;

    float acc[8][8];
#pragma unroll
    for (int i = 0; i < 8; i++)
#pragma unroll
        for (int j = 0; j < 8; j++) acc[i][j] = 0.f;

    for (int k0 = 0; k0 < DIMM; k0 += 16) {
        // A tile: vectorized, transposed into As[k][m]
#pragma unroll
        for (int rep = 0; rep < 2; rep++) {
            int row = t / 4 + rep * 64;
            int kk  = (t % 4) * 4;
            float4 v = *reinterpret_cast<const float4*>(&fa[(size_t)(bm + row) * DIMM + k0 + kk]);
            As[kk + 0][row] = v.x; As[kk + 1][row] = v.y;
            As[kk + 2][row] = v.z; As[kk + 3][row] = v.w;
        }
        // B tile: code rows bn..bn+127, k slice k0..k0+15 (row stride 511 -> scalar loads)
#pragma unroll
        for (int rep = 0; rep < 8; rep++) {
            int k  = t % 16;
            int n  = t / 16 + rep * 16;
            int gk = k0 + k;
            int gn = bn + n;
            Bs[k][n] = (gk < DM1) ? cw[(size_t)gn * DM1 + gk] : cwb[gn];
        }
        __syncthreads();
#pragma unroll
        for (int k = 0; k < 16; k++) {
            float a[8], b[8];
            *reinterpret_cast<float4*>(&a[0]) = *reinterpret_cast<const float4*>(&As[k][ty * 4]);
            *reinterpret_cast<float4*>(&a[4]) = *reinterpret_cast<const float4*>(&As[k][ty * 4 + 64]);
            *reinterpret_cast<float4*>(&b[0]) = *reinterpret_cast<const float4*>(&Bs[k][tx * 4]);
            *reinterpret_cast<float4*>(&b[4]) = *reinterpret_cast<const float4*>(&Bs[k][tx * 4 + 64]);
#pragma unroll
            for (int i = 0; i < 8; i++)
#pragma unroll
                for (int j = 0; j < 8; j++) acc[i][j] += a[i] * b[j];
        }
        __syncthreads();
    }

    // epilogue: exp2, store logits, per-row partial sums
    float rpart[8];
#pragma unroll
    for (int i = 0; i < 8; i++) {
        int m = bm + ty * 4 + (i & 3) + (i >> 2) * 64;
        float rs = 0.f;
#pragma unroll
        for (int j = 0; j < 8; j++) {
            int n = bn + tx * 4 + (j & 3) + (j >> 2) * 64;
            float l = exp2f(acc[i][j]);
            logits[(size_t)m * NC + n] = l;
            rs += l;
        }
        rpart[i] = rs;
    }
    // reduce across the 16 lanes (tx) sharing each row group
#pragma unroll
    for (int i = 0; i < 8; i++) {
        float v = rpart[i];
        v += __shfl_xor(v, 1, 64);
        v += __shfl_xor(v, 2, 64);
        v += __shfl_xor(v, 4, 64);
        v += __shfl_xor(v, 8, 64);
        rpart[i] = v;
    }
    if (tx == 0) {
#pragma unroll
        for (int i = 0; i < 8; i++) {
            int m = bm + ty * 4 + (i & 3) + (i >> 2) * 64;
            atomicAdd(&row_sum[m], rpart[i]);
        }
    }
}

// ---------------------------------------------------------------------------
// Small reduction kernels
// ---------------------------------------------------------------------------
__device__ __forceinline__ float wave_reduce(float v)
{
    v += __shfl_xor(v, 1, 64);
    v += __shfl_xor(v, 2, 64);
    v += __shfl_xor(v, 4, 64);
    v += __shfl_xor(v, 8, 64);
    v += __shfl_xor(v, 16, 64);
    v += __shfl_xor(v, 32, 64);
    return v;
}

__device__ __forceinline__ float block_reduce_256(float v)
{
    __shared__ float sw[4];
    v = wave_reduce(v);
    int wid = threadIdx.x >> 6;
    if ((threadIdx.x & 63) == 0) sw[wid] = v;
    __syncthreads();
    if (threadIdx.x == 0) v = sw[0] + sw[1] + sw[2] + sw[3];
    return v;   // valid in thread 0 only
}

// mask is a JAX bool converted by the harness to int32 (integer -> const int*).
// Round-1 post-mortem: reading it as bytes undercounted num_masked 4x ->
// survival_loss scaled 4.00x -> absmax 11.03. int32 read fixes it.
__global__ void mask_reduce_kernel(const int* __restrict__ mask, float* __restrict__ scal)
{
    float s = 0.f;
    for (int i = threadIdx.x; i < B_; i += 256) s += (mask[i] != 0) ? 1.f : 0.f;
    s = block_reduce_256(s);
    if (threadIdx.x == 0) scal[0] = s;
}

__global__ void base_reduce_kernel(const float* __restrict__ defs,
                                   const float* __restrict__ row_sum,
                                   float* __restrict__ scal)
{
    float s = 0.f;
    for (int i = threadIdx.x; i < M_; i += 256) s += exp2f(defs[i]) * row_sum[i];
    s = block_reduce_256(s);
    if (threadIdx.x == 0) scal[1] = s;
}

__global__ void corr_kernel(const int* __restrict__ rows, const int* __restrict__ cols,
                            const float* __restrict__ vals, const float* __restrict__ defs,
                            const float* __restrict__ logits, float* __restrict__ scal)
{
    int idx = blockIdx.x * blockDim.x + threadIdx.x;
    float c = 0.f;
    for (int k = idx; k < NNZ_; k += gridDim.x * blockDim.x) {
        int r  = rows[k];
        int cc = cols[k];
        float lg = logits[(size_t)r * NC + cc];
        c += lg * (exp2f(vals[k]) - exp2f(defs[r]));
    }
    c = wave_reduce(c);
    if ((threadIdx.x & 63) == 0) atomicAdd(&scal[2], c);
}

// one wave per event: dot(full_a[r], tcw[c]) over 512 elems
__global__ void event_kernel(const int* __restrict__ ev,
                             const float* __restrict__ fa,
                             const float* __restrict__ cw,
                             const float* __restrict__ cwb,
                             float* __restrict__ scal)
{
    int wid  = (blockIdx.x * blockDim.x + threadIdx.x) >> 6;
    int lane = threadIdx.x & 63;
    if (wid >= NEV) return;
    int r = ev[wid * 2 + 0];
    int c = ev[wid * 2 + 1];
    const float* a = &fa[(size_t)r * DIMM];
    const float* w = &cw[(size_t)c * DM1];
    float s = 0.f;
#pragma unroll
    for (int u = 0; u < 8; u++) {
        int d = u * 64 + lane;
        s += (d < DM1) ? a[d] * w[d] : cwb[c];   // d==511: a[511]=1, tcw col = bias
    }
    s = wave_reduce(s);
    if (lane == 0) atomicAdd(&scal[3], s);
}

__global__ void final_kernel(const float* __restrict__ scal, float* __restrict__ out)
{
    if (threadIdx.x == 0) {
        float nm   = scal[0];
        float base = scal[1];
        float corr = scal[2];
        float evs  = scal[3];
        float exp_mean   = (base + corr) / ((float)M_ * (float)NC);
        float survival   = exp_mean * ((float)M_ / nm);
        float event_loss = -0.69314718055994530942f * evs / (nm * (float)NC);
        out[0] = event_loss + survival;
    }
}

// ---------------------------------------------------------------------------
extern "C" void kernel_launch(void* const* d_in, const int* in_sizes, int n_in,
                              void* d_out, int out_size, void* d_ws, size_t ws_size,
                              hipStream_t stream)
{
    const float* features = (const float*)d_in[0];
    const int*   mask     = (const int*)d_in[1];   // jax bool -> int32 per harness
    const float* code_weight      = (const float*)d_in[2];
    const float* code_weight_bias = (const float*)d_in[3];
    const float* final_W = (const float*)d_in[4];
    const float* final_b = (const float*)d_in[5];
    const int*   sparse_rows = (const int*)d_in[6];
    const int*   sparse_cols = (const int*)d_in[7];
    const float* sparse_defaults = (const float*)d_in[8];
    const float* sparse_values   = (const float*)d_in[9];
    const int*   event_indices   = (const int*)d_in[10];

    float* out    = (float*)d_out;
    float* logits = out + 1;

    float* ws      = (float*)d_ws;
    float* scal    = ws;                 // 4 scalars used
    float* row_sum = ws + WS_ROWSUM;     // [8192]
    float* fa      = ws + WS_FULLA;      // [8192][512]

    // zero scalars + row_sum
    hipMemsetAsync(d_ws, 0, (WS_FULLA) * sizeof(float), stream);

    gemm1_kernel<<<dim3(32, 8), 256, 0, stream>>>(features, final_W, final_b, fa);
    fill_ones_kernel<<<dim3(32), 256, 0, stream>>>(fa);
    gemm2_kernel<<<dim3(64, 64), 256, 0, stream>>>(fa, code_weight, code_weight_bias,
                                                   logits, row_sum);
    mask_reduce_kernel<<<dim3(1), 256, 0, stream>>>(mask, scal);
    base_reduce_kernel<<<dim3(1), 256, 0, stream>>>(sparse_defaults, row_sum, scal);
    corr_kernel<<<dim3(64), 256, 0, stream>>>(sparse_rows, sparse_cols, sparse_values,
                                              sparse_defaults, logits, scal);
    event_kernel<<<dim3(NEV / 4), 256, 0, stream>>>(event_indices, fa, code_weight,
                                                    code_weight_bias, scal);
    final_kernel<<<dim3(1), 64, 0, stream>>>(scal, out);
}

// Round 3
// 860.645 us; speedup vs baseline: 1.7465x; 1.7465x over previous
//
#include <hip/hip_runtime.h>
#include <math.h>

typedef unsigned int u32;
typedef unsigned short u16;
typedef __attribute__((ext_vector_type(8))) __bf16 bf16x8;   // 4 VGPRs, MFMA A/B operand
typedef __attribute__((ext_vector_type(4))) float f32x4;     // MFMA C/D operand

// Problem dims
#define B_     1024
#define T_     8
#define DIMM   512
#define DM1    511
#define NC     8192
#define M_     8192
#define NNZ_   65536
#define NEV    16384
#define K1_    768
#define N1_    4088

// Workspace layout (bytes):
//   [0, 256)        scal: 0=num_masked 1=base 2=corr 3=evsum
//   fa_hi / fa_lo   [8192][512] bf16 (8 MB each)
//   tcw_hi / tcw_lo [8192][512] bf16 (8 MB each), bias folded into col 511
#define WS_SCAL   0
#define WS_FAHI   256
#define WS_FALO   (WS_FAHI + 8388608)
#define WS_TCWHI  (WS_FALO + 8388608)
#define WS_TCWLO  (WS_TCWHI + 8388608)

// ---------------------------------------------------------------------------
// bf16 split helpers (manual RNE, bit-exact and dependency-free)
// ---------------------------------------------------------------------------
__device__ __forceinline__ u16 f2bf(float x) {
    union { float f; u32 u; } v; v.f = x;
    u32 r = v.u + 0x7FFFu + ((v.u >> 16) & 1u);
    return (u16)(r >> 16);
}
__device__ __forceinline__ float bf2f(u16 h) {
    union { u32 u; float f; } v; v.u = ((u32)h) << 16;
    return v.f;
}

__device__ __forceinline__ float wave_reduce(float v) {
    v += __shfl_xor(v, 1, 64);
    v += __shfl_xor(v, 2, 64);
    v += __shfl_xor(v, 4, 64);
    v += __shfl_xor(v, 8, 64);
    v += __shfl_xor(v, 16, 64);
    v += __shfl_xor(v, 32, 64);
    return v;
}

// direct global->LDS, 16B per lane; LDS dest is wave-uniform base + lane*16
#define GLOAD16(gp, lp) __builtin_amdgcn_global_load_lds(                      \
    (const u32 __attribute__((address_space(1)))*)(gp),                        \
    (u32 __attribute__((address_space(3)))*)(lp), 16, 0, 0)

// ---------------------------------------------------------------------------
// tcw_convert: [8192][511] cw + [8192] cwb -> hi/lo bf16 [8192][512]
// ---------------------------------------------------------------------------
__global__ void tcw_convert_kernel(const float* __restrict__ cw,
                                   const float* __restrict__ cwb,
                                   u16* __restrict__ th, u16* __restrict__ tl)
{
    int idx = blockIdx.x * 256 + threadIdx.x;     // 0 .. 8192*512
    int r = idx >> 9, c = idx & 511;
    float x = (c < DM1) ? cw[(size_t)r * DM1 + c] : cwb[r];
    u16 h = f2bf(x);
    th[idx] = h;
    tl[idx] = f2bf(x - bf2f(h));
}

// ---------------------------------------------------------------------------
// GEMM1 (fp32 vector, 64x64 tile, 1024 blocks): features @ final_W + bias,
// epilogue splits to bf16 hi/lo and scatters into fa layout.
// ---------------------------------------------------------------------------
__global__ __launch_bounds__(256) void gemm1_kernel(
    const float* __restrict__ A,    // features [1024][768]
    const float* __restrict__ W,    // final_W  [768][4088]
    const float* __restrict__ bias, // final_b  [4088]
    u16* __restrict__ fh, u16* __restrict__ fl)  // fa hi/lo [8192][512]
{
    __shared__ float As[16][68];
    __shared__ float Bs[16][68];
    const int bm = blockIdx.y * 64;
    const int bn = blockIdx.x * 64;
    const int t  = threadIdx.x;
    const int tx = t & 15, ty = t >> 4;

    float acc[4][4];
#pragma unroll
    for (int i = 0; i < 4; i++)
#pragma unroll
        for (int j = 0; j < 4; j++) acc[i][j] = 0.f;

    for (int k0 = 0; k0 < K1_; k0 += 16) {
        {   // A tile 64x16 -> As[k][m] (transposed)
            int row = t >> 2, kk = (t & 3) * 4;
            float4 v = *(const float4*)&A[(size_t)(bm + row) * K1_ + k0 + kk];
            As[kk + 0][row] = v.x; As[kk + 1][row] = v.y;
            As[kk + 2][row] = v.z; As[kk + 3][row] = v.w;
        }
        {   // B tile 16x64 -> Bs[k][n]
            int k = t >> 4, n4 = (t & 15) * 4;
            int gn = bn + n4;
            float4 v;
            if (gn + 3 < N1_) {
                v = *(const float4*)&W[(size_t)(k0 + k) * N1_ + gn];
            } else {
                v.x = (gn + 0 < N1_) ? W[(size_t)(k0 + k) * N1_ + gn + 0] : 0.f;
                v.y = (gn + 1 < N1_) ? W[(size_t)(k0 + k) * N1_ + gn + 1] : 0.f;
                v.z = (gn + 2 < N1_) ? W[(size_t)(k0 + k) * N1_ + gn + 2] : 0.f;
                v.w = 0.f;
            }
            *(float4*)&Bs[k][n4] = v;
        }
        __syncthreads();
#pragma unroll
        for (int k = 0; k < 16; k++) {
            float a[4], b[4];
            *(float4*)a = *(const float4*)&As[k][ty * 4];
            *(float4*)b = *(const float4*)&Bs[k][tx * 4];
#pragma unroll
            for (int i = 0; i < 4; i++)
#pragma unroll
                for (int j = 0; j < 4; j++) acc[i][j] += a[i] * b[j];
        }
        __syncthreads();
    }

#pragma unroll
    for (int i = 0; i < 4; i++) {
        int m = bm + ty * 4 + i;
#pragma unroll
        for (int j = 0; j < 4; j++) {
            int n = bn + tx * 4 + j;
            if (n < N1_) {
                int tt = n / DM1;
                int d  = n - tt * DM1;
                float x = acc[i][j] + bias[n];
                u16 h = f2bf(x);
                size_t o = (size_t)(m * T_ + tt) * DIMM + d;
                fh[o] = h;
                fl[o] = f2bf(x - bf2f(h));
            }
        }
    }
}

// fa[:,511] = 1.0 (hi=1.0 exact, lo=0)
__global__ void fill_ones_kernel(u16* __restrict__ fh, u16* __restrict__ fl)
{
    int i = blockIdx.x * 256 + threadIdx.x;
    if (i < M_) { fh[(size_t)i * DIMM + DM1] = 0x3F80; fl[(size_t)i * DIMM + DM1] = 0; }
}

// ---------------------------------------------------------------------------
// GEMM2 split-bf16 MFMA: logits = exp2(fa @ tcw^T); base accumulated in-epilogue.
// m97 structure: 128x128 tile, BK=32, global_load_lds w16, 4 waves (2x2),
// XOR-swizzled LDS (chunk ^= (row>>2)&3) via pre-swizzled global source.
// ---------------------------------------------------------------------------
__global__ __launch_bounds__(256) void gemm2_kernel(
    const u16* __restrict__ fh, const u16* __restrict__ fl,
    const u16* __restrict__ th, const u16* __restrict__ tl,
    const float* __restrict__ defs,      // sparse_defaults [8192]
    float* __restrict__ logits,          // d_out+1 [8192][8192]
    float* __restrict__ scal)
{
    __shared__ __align__(16) u16 sAh[128 * 32];
    __shared__ __align__(16) u16 sAl[128 * 32];
    __shared__ __align__(16) u16 sBh[128 * 32];
    __shared__ __align__(16) u16 sBl[128 * 32];
    __shared__ float sdef[128];
    __shared__ float sred[4];

    const int bm = blockIdx.y * 128, bn = blockIdx.x * 128;
    const int t = threadIdx.x;
    const int l = t & 63, w = t >> 6;
    const int wm = w >> 1, wn = w & 1;          // 2x2 wave grid, each wave 64x64 out

    if (t < 128) sdef[t] = exp2f(defs[bm + t]);

    // staging lane constants: lane l -> LDS slot (row l/4, chunk l%4) linear;
    // global source chunk pre-swizzled so LDS(row,c) = G(row, c ^ ((row>>2)&3))
    const int srow   = l >> 2;
    const int schunk = (l & 3) ^ ((l >> 4) & 3);

    f32x4 acc[4][4];
#pragma unroll
    for (int mf = 0; mf < 4; mf++)
#pragma unroll
        for (int nf = 0; nf < 4; nf++) acc[mf][nf] = (f32x4){0.f, 0.f, 0.f, 0.f};

    const int fr = l & 15, ks = l >> 4;

    for (int k0 = 0; k0 < DIMM; k0 += 32) {
        // wave w stages rows [32w, 32w+32) of each of the 4 tiles
#pragma unroll
        for (int i = 0; i < 2; i++) {
            int r0 = w * 32 + i * 16;
            size_t goA = (size_t)(bm + r0 + srow) * DIMM + k0 + schunk * 8;
            size_t goB = (size_t)(bn + r0 + srow) * DIMM + k0 + schunk * 8;
            u32 lo = (u32)r0 * 32;              // element offset of row r0
            GLOAD16(fh + goA, &sAh[lo]);
            GLOAD16(fl + goA, &sAl[lo]);
            GLOAD16(th + goB, &sBh[lo]);
            GLOAD16(tl + goB, &sBl[lo]);
        }
        __syncthreads();                        // drains vmcnt, LDS visible

        const bf16x8* pAh = (const bf16x8*)sAh;
        const bf16x8* pAl = (const bf16x8*)sAl;
        const bf16x8* pBh = (const bf16x8*)sBh;
        const bf16x8* pBl = (const bf16x8*)sBl;

        bf16x8 ah[4], al[4], bh[4], bl[4];
#pragma unroll
        for (int mf = 0; mf < 4; mf++) {
            int row = wm * 64 + mf * 16 + fr;
            int c = ks ^ ((row >> 2) & 3);
            ah[mf] = pAh[row * 4 + c];
            al[mf] = pAl[row * 4 + c];
        }
#pragma unroll
        for (int nf = 0; nf < 4; nf++) {
            int row = wn * 64 + nf * 16 + fr;
            int c = ks ^ ((row >> 2) & 3);
            bh[nf] = pBh[row * 4 + c];
            bl[nf] = pBl[row * 4 + c];
        }
#pragma unroll
        for (int mf = 0; mf < 4; mf++)
#pragma unroll
            for (int nf = 0; nf < 4; nf++) {
                acc[mf][nf] = __builtin_amdgcn_mfma_f32_16x16x32_bf16(ah[mf], bh[nf], acc[mf][nf], 0, 0, 0);
                acc[mf][nf] = __builtin_amdgcn_mfma_f32_16x16x32_bf16(ah[mf], bl[nf], acc[mf][nf], 0, 0, 0);
                acc[mf][nf] = __builtin_amdgcn_mfma_f32_16x16x32_bf16(al[mf], bh[nf], acc[mf][nf], 0, 0, 0);
            }
        __syncthreads();                        // protect LDS before next stage
    }

    // epilogue: exp2, store, base-partial (C/D layout m89: row=(l>>4)*4+j, col=l&15)
    float basep = 0.f;
#pragma unroll
    for (int mf = 0; mf < 4; mf++) {
#pragma unroll
        for (int j = 0; j < 4; j++) {
            int lrow = wm * 64 + mf * 16 + ks * 4 + j;
            float ed = sdef[lrow];
            float* orow = &logits[(size_t)(bm + lrow) * NC + bn + wn * 64 + fr];
#pragma unroll
            for (int nf = 0; nf < 4; nf++) {
                float v = exp2f(acc[mf][nf][j]);
                orow[nf * 16] = v;
                basep += ed * v;
            }
        }
    }
    basep = wave_reduce(basep);
    if (l == 0) sred[w] = basep;
    __syncthreads();
    if (t == 0) atomicAdd(&scal[1], sred[0] + sred[1] + sred[2] + sred[3]);
}

// ---------------------------------------------------------------------------
// Small kernels
// ---------------------------------------------------------------------------
__global__ void mask_reduce_kernel(const int* __restrict__ mask, float* __restrict__ scal)
{
    __shared__ float sw[4];
    float s = 0.f;
    for (int i = threadIdx.x; i < B_; i += 256) s += (mask[i] != 0) ? 1.f : 0.f;
    s = wave_reduce(s);
    int wid = threadIdx.x >> 6;
    if ((threadIdx.x & 63) == 0) sw[wid] = s;
    __syncthreads();
    if (threadIdx.x == 0) scal[0] = sw[0] + sw[1] + sw[2] + sw[3];
}

__global__ void corr_kernel(const int* __restrict__ rows, const int* __restrict__ cols,
                            const float* __restrict__ vals, const float* __restrict__ defs,
                            const float* __restrict__ logits, float* __restrict__ scal)
{
    int idx = blockIdx.x * blockDim.x + threadIdx.x;
    float c = 0.f;
    for (int k = idx; k < NNZ_; k += gridDim.x * blockDim.x) {
        int r  = rows[k];
        int cc = cols[k];
        float lg = logits[(size_t)r * NC + cc];
        c += lg * (exp2f(vals[k]) - exp2f(defs[r]));
    }
    c = wave_reduce(c);
    if ((threadIdx.x & 63) == 0) atomicAdd(&scal[2], c);
}

// one wave per event: dot(fa[r], tcw_row[c]) — fa reconstructed as hi+lo
__global__ void event_kernel(const int* __restrict__ ev,
                             const u16* __restrict__ fh, const u16* __restrict__ fl,
                             const float* __restrict__ cw, const float* __restrict__ cwb,
                             float* __restrict__ scal)
{
    int wid  = (blockIdx.x * blockDim.x + threadIdx.x) >> 6;
    int lane = threadIdx.x & 63;
    if (wid >= NEV) return;
    int r = ev[wid * 2 + 0];
    int c = ev[wid * 2 + 1];
    const u16* ah = &fh[(size_t)r * DIMM];
    const u16* al = &fl[(size_t)r * DIMM];
    const float* wv = &cw[(size_t)c * DM1];
    float s = 0.f;
#pragma unroll
    for (int u = 0; u < 8; u++) {
        int d = u * 64 + lane;
        float a = bf2f(ah[d]) + bf2f(al[d]);     // col 511: 1.0 + 0 exactly
        float ww = (d < DM1) ? wv[d] : cwb[c];
        s += a * ww;
    }
    s = wave_reduce(s);
    if (lane == 0) atomicAdd(&scal[3], s);
}

__global__ void final_kernel(const float* __restrict__ scal, float* __restrict__ out)
{
    if (threadIdx.x == 0) {
        float nm   = scal[0];
        float base = scal[1];
        float corr = scal[2];
        float evs  = scal[3];
        float exp_mean   = (base + corr) / ((float)M_ * (float)NC);
        float survival   = exp_mean * ((float)M_ / nm);
        float event_loss = -0.69314718055994530942f * evs / (nm * (float)NC);
        out[0] = event_loss + survival;
    }
}

// ---------------------------------------------------------------------------
extern "C" void kernel_launch(void* const* d_in, const int* in_sizes, int n_in,
                              void* d_out, int out_size, void* d_ws, size_t ws_size,
                              hipStream_t stream)
{
    const float* features = (const float*)d_in[0];
    const int*   mask     = (const int*)d_in[1];   // jax bool -> int32 (validated r2)
    const float* code_weight      = (const float*)d_in[2];
    const float* code_weight_bias = (const float*)d_in[3];
    const float* final_W = (const float*)d_in[4];
    const float* final_b = (const float*)d_in[5];
    const int*   sparse_rows = (const int*)d_in[6];
    const int*   sparse_cols = (const int*)d_in[7];
    const float* sparse_defaults = (const float*)d_in[8];
    const float* sparse_values   = (const float*)d_in[9];
    const int*   event_indices   = (const int*)d_in[10];

    float* out    = (float*)d_out;
    float* logits = out + 1;

    char* ws = (char*)d_ws;
    float* scal = (float*)(ws + WS_SCAL);
    u16* fa_hi  = (u16*)(ws + WS_FAHI);
    u16* fa_lo  = (u16*)(ws + WS_FALO);
    u16* tcw_hi = (u16*)(ws + WS_TCWHI);
    u16* tcw_lo = (u16*)(ws + WS_TCWLO);

    hipMemsetAsync(scal, 0, 256, stream);

    tcw_convert_kernel<<<dim3((NC * DIMM) / 256), 256, 0, stream>>>(
        code_weight, code_weight_bias, tcw_hi, tcw_lo);
    gemm1_kernel<<<dim3(64, 16), 256, 0, stream>>>(features, final_W, final_b, fa_hi, fa_lo);
    fill_ones_kernel<<<dim3(32), 256, 0, stream>>>(fa_hi, fa_lo);
    gemm2_kernel<<<dim3(64, 64), 256, 0, stream>>>(fa_hi, fa_lo, tcw_hi, tcw_lo,
                                                   sparse_defaults, logits, scal);
    mask_reduce_kernel<<<dim3(1), 256, 0, stream>>>(mask, scal);
    corr_kernel<<<dim3(256), 256, 0, stream>>>(sparse_rows, sparse_cols, sparse_values,
                                               sparse_defaults, logits, scal);
    event_kernel<<<dim3(NEV / 4), 256, 0, stream>>>(event_indices, fa_hi, fa_lo,
                                                    code_weight, code_weight_bias, scal);
    final_kernel<<<dim3(1), 64, 0, stream>>>(scal, out);
}

// Round 5
// 609.083 us; speedup vs baseline: 2.4678x; 1.4130x over previous
//
#include <hip/hip_runtime.h>
#include <math.h>

typedef unsigned int u32;
typedef unsigned short u16;
typedef __attribute__((ext_vector_type(8))) __bf16 bf16x8;   // 4 VGPRs, MFMA A/B operand
typedef __attribute__((ext_vector_type(4))) float f32x4;     // MFMA C/D operand

// Problem dims
#define B_     1024
#define T_     8
#define DIMM   512
#define DM1    511
#define NC     8192
#define M_     8192
#define NNZ_   65536
#define NEV    16384
#define K1_    768
#define N1_    4088
#define N1P    4096          // padded N for gemm1 MFMA

// Workspace layout (bytes)
#define WS_SCAL   0                         // [0..3]: 0=num_masked 1=base
#define WS_EVP    1024                      // event partials: 512 floats
#define WS_CORP   3072                      // corr partials: 256 floats
#define WS_FAHI   4096
#define WS_FALO   (WS_FAHI + 8388608)       // fa hi/lo [8192][512] bf16
#define WS_TCWHI  (WS_FALO + 8388608)
#define WS_TCWLO  (WS_TCWHI + 8388608)      // tcw hi/lo [8192][512] bf16
#define WS_FEATHI (WS_TCWLO + 8388608)
#define WS_FEATLO (WS_FEATHI + 1572864)     // features hi/lo [1024][768] bf16
#define WS_WTHI   (WS_FEATLO + 1572864)
#define WS_WTLO   (WS_WTHI + 6291456)       // final_W^T hi/lo [4096][768] bf16

// ---------------------------------------------------------------------------
__device__ __forceinline__ u16 f2bf(float x) {
    union { float f; u32 u; } v; v.f = x;
    u32 r = v.u + 0x7FFFu + ((v.u >> 16) & 1u);
    return (u16)(r >> 16);
}
__device__ __forceinline__ float bf2f(u16 h) {
    union { u32 u; float f; } v; v.u = ((u32)h) << 16;
    return v.f;
}

__device__ __forceinline__ float wave_reduce(float v) {
    v += __shfl_xor(v, 1, 64);
    v += __shfl_xor(v, 2, 64);
    v += __shfl_xor(v, 4, 64);
    v += __shfl_xor(v, 8, 64);
    v += __shfl_xor(v, 16, 64);
    v += __shfl_xor(v, 32, 64);
    return v;
}

#define GLOAD16(gp, lp) __builtin_amdgcn_global_load_lds(                      \
    (const u32 __attribute__((address_space(1)))*)(gp),                        \
    (u32 __attribute__((address_space(3)))*)(lp), 16, 0, 0)

// ---------------------------------------------------------------------------
// prep: tcw -> hi/lo [8192][512] (bias in col 511)
// ---------------------------------------------------------------------------
__global__ void tcw_convert_kernel(const float* __restrict__ cw,
                                   const float* __restrict__ cwb,
                                   u16* __restrict__ th, u16* __restrict__ tl)
{
    int idx = blockIdx.x * 256 + threadIdx.x;     // 0 .. 8192*512
    int r = idx >> 9, c = idx & 511;
    float x = (c < DM1) ? cw[(size_t)r * DM1 + c] : cwb[r];
    u16 h = f2bf(x);
    th[idx] = h;
    tl[idx] = f2bf(x - bf2f(h));
}

// prep: features -> hi/lo [1024][768]
__global__ void feat_convert_kernel(const float* __restrict__ A,
                                    u16* __restrict__ ah, u16* __restrict__ al)
{
    int idx = blockIdx.x * 256 + threadIdx.x;     // 0 .. 1024*768
    float x = A[idx];
    u16 h = f2bf(x);
    ah[idx] = h;
    al[idx] = f2bf(x - bf2f(h));
}

// prep: final_W [768][4088] -> W^T hi/lo [4096][768] (rows 4088..4095 zero)
__global__ __launch_bounds__(256) void wt_convert_kernel(const float* __restrict__ W,
                                                         u16* __restrict__ wh,
                                                         u16* __restrict__ wl)
{
    __shared__ float tile[32][33];
    const int bx = blockIdx.x;           // n tile: 0..127
    const int by = blockIdx.y;           // k tile: 0..23
    const int tx = threadIdx.x & 31, ty = threadIdx.x >> 5;   // 32 x 8
#pragma unroll
    for (int i = 0; i < 4; i++) {
        int k = by * 32 + ty + i * 8;
        int n = bx * 32 + tx;
        tile[ty + i * 8][tx] = (n < N1_) ? W[(size_t)k * N1_ + n] : 0.f;
    }
    __syncthreads();
#pragma unroll
    for (int i = 0; i < 4; i++) {
        int n2 = bx * 32 + ty + i * 8;   // output row (< 4096)
        int k2 = by * 32 + tx;           // output col
        float x = tile[tx][ty + i * 8];  // = W[k2][n2]
        u16 h = f2bf(x);
        size_t o = (size_t)n2 * K1_ + k2;
        wh[o] = h;
        wl[o] = f2bf(x - bf2f(h));
    }
}

// ---------------------------------------------------------------------------
// GEMM1 via split-bf16 MFMA (clone of proven gemm2 core):
// C[m][n] = feat[m] . wt[n], m<1024, n<4096 (stores only n<4088), K=768.
// Epilogue: + bias, split hi/lo, scatter into fa layout.
// ---------------------------------------------------------------------------
__global__ __launch_bounds__(256) void gemm1_mfma_kernel(
    const u16* __restrict__ ah_g, const u16* __restrict__ al_g,  // feat hi/lo [1024][768]
    const u16* __restrict__ bh_g, const u16* __restrict__ bl_g,  // wt hi/lo [4096][768]
    const float* __restrict__ bias,
    u16* __restrict__ fh, u16* __restrict__ fl)                  // fa hi/lo out
{
    __shared__ __align__(16) u16 sAh[128 * 32];
    __shared__ __align__(16) u16 sAl[128 * 32];
    __shared__ __align__(16) u16 sBh[128 * 32];
    __shared__ __align__(16) u16 sBl[128 * 32];

    const int bm = blockIdx.y * 128, bn = blockIdx.x * 128;
    const int t = threadIdx.x;
    const int l = t & 63, w = t >> 6;
    const int wm = w >> 1, wn = w & 1;

    const int srow   = l >> 2;
    const int schunk = (l & 3) ^ ((l >> 4) & 3);

    f32x4 acc[4][4];
#pragma unroll
    for (int mf = 0; mf < 4; mf++)
#pragma unroll
        for (int nf = 0; nf < 4; nf++) acc[mf][nf] = (f32x4){0.f, 0.f, 0.f, 0.f};

    const int fr = l & 15, ks = l >> 4;

    for (int k0 = 0; k0 < K1_; k0 += 32) {
#pragma unroll
        for (int i = 0; i < 2; i++) {
            int r0 = w * 32 + i * 16;
            size_t goA = (size_t)(bm + r0 + srow) * K1_ + k0 + schunk * 8;
            size_t goB = (size_t)(bn + r0 + srow) * K1_ + k0 + schunk * 8;
            u32 lo = (u32)r0 * 32;
            GLOAD16(ah_g + goA, &sAh[lo]);
            GLOAD16(al_g + goA, &sAl[lo]);
            GLOAD16(bh_g + goB, &sBh[lo]);
            GLOAD16(bl_g + goB, &sBl[lo]);
        }
        __syncthreads();

        const bf16x8* pAh = (const bf16x8*)sAh;
        const bf16x8* pAl = (const bf16x8*)sAl;
        const bf16x8* pBh = (const bf16x8*)sBh;
        const bf16x8* pBl = (const bf16x8*)sBl;

        bf16x8 ah[4], al[4], bh[4], bl[4];
#pragma unroll
        for (int mf = 0; mf < 4; mf++) {
            int row = wm * 64 + mf * 16 + fr;
            int c = ks ^ ((row >> 2) & 3);
            ah[mf] = pAh[row * 4 + c];
            al[mf] = pAl[row * 4 + c];
        }
#pragma unroll
        for (int nf = 0; nf < 4; nf++) {
            int row = wn * 64 + nf * 16 + fr;
            int c = ks ^ ((row >> 2) & 3);
            bh[nf] = pBh[row * 4 + c];
            bl[nf] = pBl[row * 4 + c];
        }
#pragma unroll
        for (int mf = 0; mf < 4; mf++)
#pragma unroll
            for (int nf = 0; nf < 4; nf++) {
                acc[mf][nf] = __builtin_amdgcn_mfma_f32_16x16x32_bf16(ah[mf], bh[nf], acc[mf][nf], 0, 0, 0);
                acc[mf][nf] = __builtin_amdgcn_mfma_f32_16x16x32_bf16(ah[mf], bl[nf], acc[mf][nf], 0, 0, 0);
                acc[mf][nf] = __builtin_amdgcn_mfma_f32_16x16x32_bf16(al[mf], bh[nf], acc[mf][nf], 0, 0, 0);
            }
        __syncthreads();
    }

    // epilogue: + bias, split, scatter into fa[(m*8+tt)*512+d]
#pragma unroll
    for (int mf = 0; mf < 4; mf++) {
#pragma unroll
        for (int j = 0; j < 4; j++) {
            int m = bm + wm * 64 + mf * 16 + ks * 4 + j;
#pragma unroll
            for (int nf = 0; nf < 4; nf++) {
                int n = bn + wn * 64 + nf * 16 + fr;
                if (n < N1_) {
                    float x = acc[mf][nf][j] + bias[n];
                    int tt = n / DM1;
                    int d  = n - tt * DM1;
                    u16 h = f2bf(x);
                    size_t o = (size_t)(m * T_ + tt) * DIMM + d;
                    fh[o] = h;
                    fl[o] = f2bf(x - bf2f(h));
                }
            }
        }
    }
}

// fa[:,511] = 1.0
__global__ void fill_ones_kernel(u16* __restrict__ fh, u16* __restrict__ fl)
{
    int i = blockIdx.x * 256 + threadIdx.x;
    if (i < M_) { fh[(size_t)i * DIMM + DM1] = 0x3F80; fl[(size_t)i * DIMM + DM1] = 0; }
}

// ---------------------------------------------------------------------------
// GEMM2 split-bf16 MFMA (unchanged from round 3): logits = exp2(fa @ tcw^T),
// base accumulated in-epilogue (4096 staggered atomics — not a serialization
// hot-spot since they're spread over the kernel's runtime).
// ---------------------------------------------------------------------------
__global__ __launch_bounds__(256) void gemm2_kernel(
    const u16* __restrict__ fh, const u16* __restrict__ fl,
    const u16* __restrict__ th, const u16* __restrict__ tl,
    const float* __restrict__ defs,
    float* __restrict__ logits,
    float* __restrict__ scal)
{
    __shared__ __align__(16) u16 sAh[128 * 32];
    __shared__ __align__(16) u16 sAl[128 * 32];
    __shared__ __align__(16) u16 sBh[128 * 32];
    __shared__ __align__(16) u16 sBl[128 * 32];
    __shared__ float sdef[128];
    __shared__ float sred[4];

    const int bm = blockIdx.y * 128, bn = blockIdx.x * 128;
    const int t = threadIdx.x;
    const int l = t & 63, w = t >> 6;
    const int wm = w >> 1, wn = w & 1;

    if (t < 128) sdef[t] = exp2f(defs[bm + t]);

    const int srow   = l >> 2;
    const int schunk = (l & 3) ^ ((l >> 4) & 3);

    f32x4 acc[4][4];
#pragma unroll
    for (int mf = 0; mf < 4; mf++)
#pragma unroll
        for (int nf = 0; nf < 4; nf++) acc[mf][nf] = (f32x4){0.f, 0.f, 0.f, 0.f};

    const int fr = l & 15, ks = l >> 4;

    for (int k0 = 0; k0 < DIMM; k0 += 32) {
#pragma unroll
        for (int i = 0; i < 2; i++) {
            int r0 = w * 32 + i * 16;
            size_t goA = (size_t)(bm + r0 + srow) * DIMM + k0 + schunk * 8;
            size_t goB = (size_t)(bn + r0 + srow) * DIMM + k0 + schunk * 8;
            u32 lo = (u32)r0 * 32;
            GLOAD16(fh + goA, &sAh[lo]);
            GLOAD16(fl + goA, &sAl[lo]);
            GLOAD16(th + goB, &sBh[lo]);
            GLOAD16(tl + goB, &sBl[lo]);
        }
        __syncthreads();

        const bf16x8* pAh = (const bf16x8*)sAh;
        const bf16x8* pAl = (const bf16x8*)sAl;
        const bf16x8* pBh = (const bf16x8*)sBh;
        const bf16x8* pBl = (const bf16x8*)sBl;

        bf16x8 ah[4], al[4], bh[4], bl[4];
#pragma unroll
        for (int mf = 0; mf < 4; mf++) {
            int row = wm * 64 + mf * 16 + fr;
            int c = ks ^ ((row >> 2) & 3);
            ah[mf] = pAh[row * 4 + c];
            al[mf] = pAl[row * 4 + c];
        }
#pragma unroll
        for (int nf = 0; nf < 4; nf++) {
            int row = wn * 64 + nf * 16 + fr;
            int c = ks ^ ((row >> 2) & 3);
            bh[nf] = pBh[row * 4 + c];
            bl[nf] = pBl[row * 4 + c];
        }
#pragma unroll
        for (int mf = 0; mf < 4; mf++)
#pragma unroll
            for (int nf = 0; nf < 4; nf++) {
                acc[mf][nf] = __builtin_amdgcn_mfma_f32_16x16x32_bf16(ah[mf], bh[nf], acc[mf][nf], 0, 0, 0);
                acc[mf][nf] = __builtin_amdgcn_mfma_f32_16x16x32_bf16(ah[mf], bl[nf], acc[mf][nf], 0, 0, 0);
                acc[mf][nf] = __builtin_amdgcn_mfma_f32_16x16x32_bf16(al[mf], bh[nf], acc[mf][nf], 0, 0, 0);
            }
        __syncthreads();
    }

    float basep = 0.f;
#pragma unroll
    for (int mf = 0; mf < 4; mf++) {
#pragma unroll
        for (int j = 0; j < 4; j++) {
            int lrow = wm * 64 + mf * 16 + ks * 4 + j;
            float ed = sdef[lrow];
            float* orow = &logits[(size_t)(bm + lrow) * NC + bn + wn * 64 + fr];
#pragma unroll
            for (int nf = 0; nf < 4; nf++) {
                float v = exp2f(acc[mf][nf][j]);
                orow[nf * 16] = v;
                basep += ed * v;
            }
        }
    }
    basep = wave_reduce(basep);
    if (l == 0) sred[w] = basep;
    __syncthreads();
    if (t == 0) atomicAdd(&scal[1], sred[0] + sred[1] + sred[2] + sred[3]);
}

// ---------------------------------------------------------------------------
// Small kernels — all reductions land in partial arrays (NO same-address
// atomic storms; round-3 post-mortem: 16K same-address atomicAdds ~ 100s of µs)
// ---------------------------------------------------------------------------
__global__ void mask_reduce_kernel(const int* __restrict__ mask, float* __restrict__ scal)
{
    __shared__ float sw[4];
    float s = 0.f;
    for (int i = threadIdx.x; i < B_; i += 256) s += (mask[i] != 0) ? 1.f : 0.f;
    s = wave_reduce(s);
    int wid = threadIdx.x >> 6;
    if ((threadIdx.x & 63) == 0) sw[wid] = s;
    __syncthreads();
    if (threadIdx.x == 0) scal[0] = sw[0] + sw[1] + sw[2] + sw[3];
}

// 256 blocks x 256 threads, one nnz element each -> corrpart[block]
__global__ __launch_bounds__(256) void corr_kernel(
    const int* __restrict__ rows, const int* __restrict__ cols,
    const float* __restrict__ vals, const float* __restrict__ defs,
    const float* __restrict__ logits, float* __restrict__ corrpart)
{
    __shared__ float sw[4];
    int k = blockIdx.x * 256 + threadIdx.x;
    int r  = rows[k];
    int cc = cols[k];
    float lg = logits[(size_t)r * NC + cc];
    float c = lg * (exp2f(vals[k]) - exp2f(defs[r]));
    c = wave_reduce(c);
    int wid = threadIdx.x >> 6;
    if ((threadIdx.x & 63) == 0) sw[wid] = c;
    __syncthreads();
    if (threadIdx.x == 0) corrpart[blockIdx.x] = sw[0] + sw[1] + sw[2] + sw[3];
}

// 512 blocks x 4 waves, 8 events per wave; vectorized fa loads -> evpart[block]
__global__ __launch_bounds__(256) void event_kernel(
    const int* __restrict__ ev,
    const u16* __restrict__ fh, const u16* __restrict__ fl,
    const float* __restrict__ cw, const float* __restrict__ cwb,
    float* __restrict__ evpart)
{
    __shared__ float sw[4];
    const int w = threadIdx.x >> 6, lane = threadIdx.x & 63;
    const int wg = blockIdx.x * 4 + w;           // 0..2047
    float s = 0.f;
#pragma unroll
    for (int e = 0; e < 8; e++) {
        int eid = wg * 8 + e;
        int r = ev[eid * 2 + 0];
        int c = ev[eid * 2 + 1];
        uint4 hv = *(const uint4*)(fh + (size_t)r * DIMM + lane * 8);
        uint4 lv = *(const uint4*)(fl + (size_t)r * DIMM + lane * 8);
        const float* wr = cw + (size_t)c * DM1 + lane * 8;
        const u32* hq = (const u32*)&hv;
        const u32* lq = (const u32*)&lv;
#pragma unroll
        for (int q = 0; q < 4; q++) {
            float a0 = bf2f((u16)(hq[q] & 0xffff)) + bf2f((u16)(lq[q] & 0xffff));
            float a1 = bf2f((u16)(hq[q] >> 16))    + bf2f((u16)(lq[q] >> 16));
            int d1 = lane * 8 + q * 2 + 1;
            float w0 = wr[q * 2];
            float w1 = (d1 < DM1) ? wr[q * 2 + 1] : cwb[c];
            s += a0 * w0 + a1 * w1;
        }
    }
    s = wave_reduce(s);
    if (lane == 0) sw[w] = s;
    __syncthreads();
    if (threadIdx.x == 0) evpart[blockIdx.x] = sw[0] + sw[1] + sw[2] + sw[3];
}

__global__ __launch_bounds__(256) void final_kernel(
    const float* __restrict__ scal, const float* __restrict__ evpart,
    const float* __restrict__ corrpart, float* __restrict__ out)
{
    __shared__ float swe[4], swc[4];
    int t = threadIdx.x;
    float se = evpart[t] + evpart[t + 256];
    float sc = corrpart[t];
    se = wave_reduce(se);
    sc = wave_reduce(sc);
    int w = t >> 6;
    if ((t & 63) == 0) { swe[w] = se; swc[w] = sc; }
    __syncthreads();
    if (t == 0) {
        float evs  = swe[0] + swe[1] + swe[2] + swe[3];
        float corr = swc[0] + swc[1] + swc[2] + swc[3];
        float nm   = scal[0];
        float base = scal[1];
        float exp_mean   = (base + corr) / ((float)M_ * (float)NC);
        float survival   = exp_mean * ((float)M_ / nm);
        float event_loss = -0.69314718055994530942f * evs / (nm * (float)NC);
        out[0] = event_loss + survival;
    }
}

// ---------------------------------------------------------------------------
extern "C" void kernel_launch(void* const* d_in, const int* in_sizes, int n_in,
                              void* d_out, int out_size, void* d_ws, size_t ws_size,
                              hipStream_t stream)
{
    const float* features = (const float*)d_in[0];
    const int*   mask     = (const int*)d_in[1];   // jax bool -> int32 (validated r2)
    const float* code_weight      = (const float*)d_in[2];
    const float* code_weight_bias = (const float*)d_in[3];
    const float* final_W = (const float*)d_in[4];
    const float* final_b = (const float*)d_in[5];
    const int*   sparse_rows = (const int*)d_in[6];
    const int*   sparse_cols = (const int*)d_in[7];
    const float* sparse_defaults = (const float*)d_in[8];
    const float* sparse_values   = (const float*)d_in[9];
    const int*   event_indices   = (const int*)d_in[10];

    float* out    = (float*)d_out;
    float* logits = out + 1;

    char* ws = (char*)d_ws;
    float* scal     = (float*)(ws + WS_SCAL);
    float* evpart   = (float*)(ws + WS_EVP);
    float* corrpart = (float*)(ws + WS_CORP);
    u16* fa_hi   = (u16*)(ws + WS_FAHI);
    u16* fa_lo   = (u16*)(ws + WS_FALO);
    u16* tcw_hi  = (u16*)(ws + WS_TCWHI);
    u16* tcw_lo  = (u16*)(ws + WS_TCWLO);
    u16* feat_hi = (u16*)(ws + WS_FEATHI);
    u16* feat_lo = (u16*)(ws + WS_FEATLO);
    u16* wt_hi   = (u16*)(ws + WS_WTHI);
    u16* wt_lo   = (u16*)(ws + WS_WTLO);

    hipMemsetAsync(scal, 0, 256, stream);

    tcw_convert_kernel<<<dim3((NC * DIMM) / 256), 256, 0, stream>>>(
        code_weight, code_weight_bias, tcw_hi, tcw_lo);
    feat_convert_kernel<<<dim3((B_ * K1_) / 256), 256, 0, stream>>>(
        features, feat_hi, feat_lo);
    wt_convert_kernel<<<dim3(N1P / 32, K1_ / 32), 256, 0, stream>>>(
        final_W, wt_hi, wt_lo);
    gemm1_mfma_kernel<<<dim3(N1P / 128, B_ / 128), 256, 0, stream>>>(
        feat_hi, feat_lo, wt_hi, wt_lo, final_b, fa_hi, fa_lo);
    fill_ones_kernel<<<dim3(M_ / 256), 256, 0, stream>>>(fa_hi, fa_lo);
    gemm2_kernel<<<dim3(64, 64), 256, 0, stream>>>(fa_hi, fa_lo, tcw_hi, tcw_lo,
                                                   sparse_defaults, logits, scal);
    mask_reduce_kernel<<<dim3(1), 256, 0, stream>>>(mask, scal);
    corr_kernel<<<dim3(NNZ_ / 256), 256, 0, stream>>>(sparse_rows, sparse_cols, sparse_values,
                                                      sparse_defaults, logits, corrpart);
    event_kernel<<<dim3(512), 256, 0, stream>>>(event_indices, fa_hi, fa_lo,
                                                code_weight, code_weight_bias, evpart);
    final_kernel<<<dim3(1), 256, 0, stream>>>(scal, evpart, corrpart, out);
}

// Round 6
// 584.693 us; speedup vs baseline: 2.5707x; 1.0417x over previous
//
#include <hip/hip_runtime.h>
#include <math.h>

typedef unsigned int u32;
typedef unsigned short u16;
typedef __attribute__((ext_vector_type(8))) __bf16 bf16x8;   // 4 VGPRs, MFMA A/B operand
typedef __attribute__((ext_vector_type(4))) float f32x4;     // MFMA C/D operand

// Problem dims
#define B_     1024
#define T_     8
#define DIMM   512
#define DM1    511
#define NC     8192
#define M_     8192
#define NNZ_   65536
#define NEV    16384
#define K1_    768
#define N1_    4088
#define N1P    4096          // padded N for gemm1 MFMA

// Workspace layout (bytes)
#define WS_SCAL   0                         // [1]=base (gemm2 atomic)
#define WS_EVP    1024                      // event partials: 512 floats
#define WS_CORP   3072                      // corr partials: 256 floats
#define WS_FAHI   4096
#define WS_FALO   (WS_FAHI + 8388608)       // fa hi/lo [8192][512] bf16
#define WS_TCWHI  (WS_FALO + 8388608)
#define WS_TCWLO  (WS_TCWHI + 8388608)      // tcw hi/lo [8192][512] bf16
#define WS_FEATHI (WS_TCWLO + 8388608)
#define WS_FEATLO (WS_FEATHI + 1572864)     // features hi/lo [1024][768] bf16
#define WS_WTHI   (WS_FEATLO + 1572864)
#define WS_WTLO   (WS_WTHI + 6291456)       // final_W^T hi/lo [4096][768] bf16

// ---------------------------------------------------------------------------
__device__ __forceinline__ u16 f2bf(float x) {
    union { float f; u32 u; } v; v.f = x;
    u32 r = v.u + 0x7FFFu + ((v.u >> 16) & 1u);
    return (u16)(r >> 16);
}
__device__ __forceinline__ float bf2f(u16 h) {
    union { u32 u; float f; } v; v.u = ((u32)h) << 16;
    return v.f;
}

__device__ __forceinline__ float wave_reduce(float v) {
    v += __shfl_xor(v, 1, 64);
    v += __shfl_xor(v, 2, 64);
    v += __shfl_xor(v, 4, 64);
    v += __shfl_xor(v, 8, 64);
    v += __shfl_xor(v, 16, 64);
    v += __shfl_xor(v, 32, 64);
    return v;
}

#define GLOAD16(gp, lp) __builtin_amdgcn_global_load_lds(                      \
    (const u32 __attribute__((address_space(1)))*)(gp),                        \
    (u32 __attribute__((address_space(3)))*)(lp), 16, 0, 0)

// ---------------------------------------------------------------------------
// prep: tcw -> hi/lo [8192][512] (bias in col 511)
// ---------------------------------------------------------------------------
__global__ void tcw_convert_kernel(const float* __restrict__ cw,
                                   const float* __restrict__ cwb,
                                   u16* __restrict__ th, u16* __restrict__ tl)
{
    int idx = blockIdx.x * 256 + threadIdx.x;     // 0 .. 8192*512
    int r = idx >> 9, c = idx & 511;
    float x = (c < DM1) ? cw[(size_t)r * DM1 + c] : cwb[r];
    u16 h = f2bf(x);
    th[idx] = h;
    tl[idx] = f2bf(x - bf2f(h));
}

// prep: features -> hi/lo [1024][768]
__global__ void feat_convert_kernel(const float* __restrict__ A,
                                    u16* __restrict__ ah, u16* __restrict__ al)
{
    int idx = blockIdx.x * 256 + threadIdx.x;     // 0 .. 1024*768
    float x = A[idx];
    u16 h = f2bf(x);
    ah[idx] = h;
    al[idx] = f2bf(x - bf2f(h));
}

// prep: final_W [768][4088] -> W^T hi/lo [4096][768] (rows 4088..4095 zero)
__global__ __launch_bounds__(256) void wt_convert_kernel(const float* __restrict__ W,
                                                         u16* __restrict__ wh,
                                                         u16* __restrict__ wl)
{
    __shared__ float tile[32][33];
    const int bx = blockIdx.x;           // n tile: 0..127
    const int by = blockIdx.y;           // k tile: 0..23
    const int tx = threadIdx.x & 31, ty = threadIdx.x >> 5;   // 32 x 8
#pragma unroll
    for (int i = 0; i < 4; i++) {
        int k = by * 32 + ty + i * 8;
        int n = bx * 32 + tx;
        tile[ty + i * 8][tx] = (n < N1_) ? W[(size_t)k * N1_ + n] : 0.f;
    }
    __syncthreads();
#pragma unroll
    for (int i = 0; i < 4; i++) {
        int n2 = bx * 32 + ty + i * 8;   // output row (< 4096)
        int k2 = by * 32 + tx;           // output col
        float x = tile[tx][ty + i * 8];  // = W[k2][n2]
        u16 h = f2bf(x);
        size_t o = (size_t)n2 * K1_ + k2;
        wh[o] = h;
        wl[o] = f2bf(x - bf2f(h));
    }
}

// ---------------------------------------------------------------------------
// GEMM1 split-bf16 MFMA, 64x128 tile, 512 blocks (round-6: was 128x128/256
// blocks = 1 block/CU = 1 wave/SIMD -> barrier drain unhidden).
// Wave (wm,wn) 2x2; each wave outputs 32x64. acc[2][4]. LDS 24 KB.
// ---------------------------------------------------------------------------
__global__ __launch_bounds__(256) void gemm1_mfma_kernel(
    const u16* __restrict__ ah_g, const u16* __restrict__ al_g,  // feat hi/lo [1024][768]
    const u16* __restrict__ bh_g, const u16* __restrict__ bl_g,  // wt hi/lo [4096][768]
    const float* __restrict__ bias,
    u16* __restrict__ fh, u16* __restrict__ fl)                  // fa hi/lo out
{
    __shared__ __align__(16) u16 sAh[64 * 32];
    __shared__ __align__(16) u16 sAl[64 * 32];
    __shared__ __align__(16) u16 sBh[128 * 32];
    __shared__ __align__(16) u16 sBl[128 * 32];

    const int bm = blockIdx.y * 64, bn = blockIdx.x * 128;
    const int t = threadIdx.x;
    const int l = t & 63, w = t >> 6;
    const int wm = w >> 1, wn = w & 1;

    const int srow   = l >> 2;                      // 0..15
    const int schunk = (l & 3) ^ ((l >> 4) & 3);    // XOR key valid: wave row-bases %16==0

    f32x4 acc[2][4];
#pragma unroll
    for (int mf = 0; mf < 2; mf++)
#pragma unroll
        for (int nf = 0; nf < 4; nf++) acc[mf][nf] = (f32x4){0.f, 0.f, 0.f, 0.f};

    const int fr = l & 15, ks = l >> 4;

    for (int k0 = 0; k0 < K1_; k0 += 32) {
        {   // A tile 64x32: wave w stages rows [16w,16w+16)
            size_t goA = (size_t)(bm + w * 16 + srow) * K1_ + k0 + schunk * 8;
            u32 lo = (u32)(w * 16) * 32;
            GLOAD16(ah_g + goA, &sAh[lo]);
            GLOAD16(al_g + goA, &sAl[lo]);
        }
#pragma unroll
        for (int i = 0; i < 2; i++) {   // B tile 128x32: wave w stages rows [32w,32w+32)
            int r0 = w * 32 + i * 16;
            size_t goB = (size_t)(bn + r0 + srow) * K1_ + k0 + schunk * 8;
            u32 lo = (u32)r0 * 32;
            GLOAD16(bh_g + goB, &sBh[lo]);
            GLOAD16(bl_g + goB, &sBl[lo]);
        }
        __syncthreads();

        const bf16x8* pAh = (const bf16x8*)sAh;
        const bf16x8* pAl = (const bf16x8*)sAl;
        const bf16x8* pBh = (const bf16x8*)sBh;
        const bf16x8* pBl = (const bf16x8*)sBl;

        bf16x8 ah[2], al[2], bh[4], bl[4];
#pragma unroll
        for (int mf = 0; mf < 2; mf++) {
            int row = wm * 32 + mf * 16 + fr;
            int c = ks ^ ((row >> 2) & 3);
            ah[mf] = pAh[row * 4 + c];
            al[mf] = pAl[row * 4 + c];
        }
#pragma unroll
        for (int nf = 0; nf < 4; nf++) {
            int row = wn * 64 + nf * 16 + fr;
            int c = ks ^ ((row >> 2) & 3);
            bh[nf] = pBh[row * 4 + c];
            bl[nf] = pBl[row * 4 + c];
        }
#pragma unroll
        for (int mf = 0; mf < 2; mf++)
#pragma unroll
            for (int nf = 0; nf < 4; nf++) {
                acc[mf][nf] = __builtin_amdgcn_mfma_f32_16x16x32_bf16(ah[mf], bh[nf], acc[mf][nf], 0, 0, 0);
                acc[mf][nf] = __builtin_amdgcn_mfma_f32_16x16x32_bf16(ah[mf], bl[nf], acc[mf][nf], 0, 0, 0);
                acc[mf][nf] = __builtin_amdgcn_mfma_f32_16x16x32_bf16(al[mf], bh[nf], acc[mf][nf], 0, 0, 0);
            }
        __syncthreads();
    }

    // epilogue: + bias, split hi/lo, scatter into fa[(m*8+tt)*512+d]
#pragma unroll
    for (int mf = 0; mf < 2; mf++) {
#pragma unroll
        for (int j = 0; j < 4; j++) {
            int m = bm + wm * 32 + mf * 16 + ks * 4 + j;
#pragma unroll
            for (int nf = 0; nf < 4; nf++) {
                int n = bn + wn * 64 + nf * 16 + fr;
                if (n < N1_) {
                    float x = acc[mf][nf][j] + bias[n];
                    int tt = n / DM1;
                    int d  = n - tt * DM1;
                    u16 h = f2bf(x);
                    size_t o = (size_t)(m * T_ + tt) * DIMM + d;
                    fh[o] = h;
                    fl[o] = f2bf(x - bf2f(h));
                }
            }
        }
    }
}

// fa[:,511] = 1.0
__global__ void fill_ones_kernel(u16* __restrict__ fh, u16* __restrict__ fl)
{
    int i = blockIdx.x * 256 + threadIdx.x;
    if (i < M_) { fh[(size_t)i * DIMM + DM1] = 0x3F80; fl[(size_t)i * DIMM + DM1] = 0; }
}

// ---------------------------------------------------------------------------
// GEMM2 split-bf16 MFMA (FROZEN since round 3): logits = exp2(fa @ tcw^T),
// base accumulated in-epilogue.
// ---------------------------------------------------------------------------
__global__ __launch_bounds__(256) void gemm2_kernel(
    const u16* __restrict__ fh, const u16* __restrict__ fl,
    const u16* __restrict__ th, const u16* __restrict__ tl,
    const float* __restrict__ defs,
    float* __restrict__ logits,
    float* __restrict__ scal)
{
    __shared__ __align__(16) u16 sAh[128 * 32];
    __shared__ __align__(16) u16 sAl[128 * 32];
    __shared__ __align__(16) u16 sBh[128 * 32];
    __shared__ __align__(16) u16 sBl[128 * 32];
    __shared__ float sdef[128];
    __shared__ float sred[4];

    const int bm = blockIdx.y * 128, bn = blockIdx.x * 128;
    const int t = threadIdx.x;
    const int l = t & 63, w = t >> 6;
    const int wm = w >> 1, wn = w & 1;

    if (t < 128) sdef[t] = exp2f(defs[bm + t]);

    const int srow   = l >> 2;
    const int schunk = (l & 3) ^ ((l >> 4) & 3);

    f32x4 acc[4][4];
#pragma unroll
    for (int mf = 0; mf < 4; mf++)
#pragma unroll
        for (int nf = 0; nf < 4; nf++) acc[mf][nf] = (f32x4){0.f, 0.f, 0.f, 0.f};

    const int fr = l & 15, ks = l >> 4;

    for (int k0 = 0; k0 < DIMM; k0 += 32) {
#pragma unroll
        for (int i = 0; i < 2; i++) {
            int r0 = w * 32 + i * 16;
            size_t goA = (size_t)(bm + r0 + srow) * DIMM + k0 + schunk * 8;
            size_t goB = (size_t)(bn + r0 + srow) * DIMM + k0 + schunk * 8;
            u32 lo = (u32)r0 * 32;
            GLOAD16(fh + goA, &sAh[lo]);
            GLOAD16(fl + goA, &sAl[lo]);
            GLOAD16(th + goB, &sBh[lo]);
            GLOAD16(tl + goB, &sBl[lo]);
        }
        __syncthreads();

        const bf16x8* pAh = (const bf16x8*)sAh;
        const bf16x8* pAl = (const bf16x8*)sAl;
        const bf16x8* pBh = (const bf16x8*)sBh;
        const bf16x8* pBl = (const bf16x8*)sBl;

        bf16x8 ah[4], al[4], bh[4], bl[4];
#pragma unroll
        for (int mf = 0; mf < 4; mf++) {
            int row = wm * 64 + mf * 16 + fr;
            int c = ks ^ ((row >> 2) & 3);
            ah[mf] = pAh[row * 4 + c];
            al[mf] = pAl[row * 4 + c];
        }
#pragma unroll
        for (int nf = 0; nf < 4; nf++) {
            int row = wn * 64 + nf * 16 + fr;
            int c = ks ^ ((row >> 2) & 3);
            bh[nf] = pBh[row * 4 + c];
            bl[nf] = pBl[row * 4 + c];
        }
#pragma unroll
        for (int mf = 0; mf < 4; mf++)
#pragma unroll
            for (int nf = 0; nf < 4; nf++) {
                acc[mf][nf] = __builtin_amdgcn_mfma_f32_16x16x32_bf16(ah[mf], bh[nf], acc[mf][nf], 0, 0, 0);
                acc[mf][nf] = __builtin_amdgcn_mfma_f32_16x16x32_bf16(ah[mf], bl[nf], acc[mf][nf], 0, 0, 0);
                acc[mf][nf] = __builtin_amdgcn_mfma_f32_16x16x32_bf16(al[mf], bh[nf], acc[mf][nf], 0, 0, 0);
            }
        __syncthreads();
    }

    float basep = 0.f;
#pragma unroll
    for (int mf = 0; mf < 4; mf++) {
#pragma unroll
        for (int j = 0; j < 4; j++) {
            int lrow = wm * 64 + mf * 16 + ks * 4 + j;
            float ed = sdef[lrow];
            float* orow = &logits[(size_t)(bm + lrow) * NC + bn + wn * 64 + fr];
#pragma unroll
            for (int nf = 0; nf < 4; nf++) {
                float v = exp2f(acc[mf][nf][j]);
                orow[nf * 16] = v;
                basep += ed * v;
            }
        }
    }
    basep = wave_reduce(basep);
    if (l == 0) sred[w] = basep;
    __syncthreads();
    if (t == 0) atomicAdd(&scal[1], sred[0] + sred[1] + sred[2] + sred[3]);
}

// ---------------------------------------------------------------------------
// Small kernels
// ---------------------------------------------------------------------------
// 256 blocks x 256 threads, one nnz element each -> corrpart[block]
__global__ __launch_bounds__(256) void corr_kernel(
    const int* __restrict__ rows, const int* __restrict__ cols,
    const float* __restrict__ vals, const float* __restrict__ defs,
    const float* __restrict__ logits, float* __restrict__ corrpart)
{
    __shared__ float sw[4];
    int k = blockIdx.x * 256 + threadIdx.x;
    int r  = rows[k];
    int cc = cols[k];
    float lg = logits[(size_t)r * NC + cc];
    float c = lg * (exp2f(vals[k]) - exp2f(defs[r]));
    c = wave_reduce(c);
    int wid = threadIdx.x >> 6;
    if ((threadIdx.x & 63) == 0) sw[wid] = c;
    __syncthreads();
    if (threadIdx.x == 0) corrpart[blockIdx.x] = sw[0] + sw[1] + sw[2] + sw[3];
}

// 512 blocks x 4 waves, 8 events/wave; fully-vectorized uint4 loads on
// fa hi/lo and tcw hi/lo (bias at col 511; hi+lo ~ fp32 to 2^-17 -> loss
// error ~1e-9, negligible). Round-6: was branchy scalar cw loads.
__global__ __launch_bounds__(256) void event_kernel(
    const int* __restrict__ ev,
    const u16* __restrict__ fh, const u16* __restrict__ fl,
    const u16* __restrict__ th, const u16* __restrict__ tl,
    float* __restrict__ evpart)
{
    __shared__ float sw[4];
    const int w = threadIdx.x >> 6, lane = threadIdx.x & 63;
    const int wg = blockIdx.x * 4 + w;           // 0..2047
    float s = 0.f;
#pragma unroll
    for (int e = 0; e < 8; e++) {
        int eid = wg * 8 + e;
        int r = ev[eid * 2 + 0];
        int c = ev[eid * 2 + 1];
        uint4 ahv = *(const uint4*)(fh + (size_t)r * DIMM + lane * 8);
        uint4 alv = *(const uint4*)(fl + (size_t)r * DIMM + lane * 8);
        uint4 bhv = *(const uint4*)(th + (size_t)c * DIMM + lane * 8);
        uint4 blv = *(const uint4*)(tl + (size_t)c * DIMM + lane * 8);
        const u32* ah = (const u32*)&ahv;
        const u32* al = (const u32*)&alv;
        const u32* bh = (const u32*)&bhv;
        const u32* bl = (const u32*)&blv;
#pragma unroll
        for (int q = 0; q < 4; q++) {
            float a0 = bf2f((u16)(ah[q] & 0xffff)) + bf2f((u16)(al[q] & 0xffff));
            float a1 = bf2f((u16)(ah[q] >> 16))    + bf2f((u16)(al[q] >> 16));
            float b0 = bf2f((u16)(bh[q] & 0xffff)) + bf2f((u16)(bl[q] & 0xffff));
            float b1 = bf2f((u16)(bh[q] >> 16))    + bf2f((u16)(bl[q] >> 16));
            s += a0 * b0 + a1 * b1;
        }
    }
    s = wave_reduce(s);
    if (lane == 0) sw[w] = s;
    __syncthreads();
    if (threadIdx.x == 0) evpart[blockIdx.x] = sw[0] + sw[1] + sw[2] + sw[3];
}

// final: fuses mask count (round-6: was its own launch)
__global__ __launch_bounds__(256) void final_kernel(
    const int* __restrict__ mask, const float* __restrict__ scal,
    const float* __restrict__ evpart, const float* __restrict__ corrpart,
    float* __restrict__ out)
{
    __shared__ float swe[4], swc[4], swm[4];
    int t = threadIdx.x;
    float se = evpart[t] + evpart[t + 256];
    float sc = corrpart[t];
    float sm = 0.f;
    for (int i = t; i < B_; i += 256) sm += (mask[i] != 0) ? 1.f : 0.f;
    se = wave_reduce(se);
    sc = wave_reduce(sc);
    sm = wave_reduce(sm);
    int w = t >> 6;
    if ((t & 63) == 0) { swe[w] = se; swc[w] = sc; swm[w] = sm; }
    __syncthreads();
    if (t == 0) {
        float evs  = swe[0] + swe[1] + swe[2] + swe[3];
        float corr = swc[0] + swc[1] + swc[2] + swc[3];
        float nm   = swm[0] + swm[1] + swm[2] + swm[3];
        float base = scal[1];
        float exp_mean   = (base + corr) / ((float)M_ * (float)NC);
        float survival   = exp_mean * ((float)M_ / nm);
        float event_loss = -0.69314718055994530942f * evs / (nm * (float)NC);
        out[0] = event_loss + survival;
    }
}

// ---------------------------------------------------------------------------
extern "C" void kernel_launch(void* const* d_in, const int* in_sizes, int n_in,
                              void* d_out, int out_size, void* d_ws, size_t ws_size,
                              hipStream_t stream)
{
    const float* features = (const float*)d_in[0];
    const int*   mask     = (const int*)d_in[1];   // jax bool -> int32 (validated r2)
    const float* code_weight      = (const float*)d_in[2];
    const float* code_weight_bias = (const float*)d_in[3];
    const float* final_W = (const float*)d_in[4];
    const float* final_b = (const float*)d_in[5];
    const int*   sparse_rows = (const int*)d_in[6];
    const int*   sparse_cols = (const int*)d_in[7];
    const float* sparse_defaults = (const float*)d_in[8];
    const float* sparse_values   = (const float*)d_in[9];
    const int*   event_indices   = (const int*)d_in[10];

    float* out    = (float*)d_out;
    float* logits = out + 1;

    char* ws = (char*)d_ws;
    float* scal     = (float*)(ws + WS_SCAL);
    float* evpart   = (float*)(ws + WS_EVP);
    float* corrpart = (float*)(ws + WS_CORP);
    u16* fa_hi   = (u16*)(ws + WS_FAHI);
    u16* fa_lo   = (u16*)(ws + WS_FALO);
    u16* tcw_hi  = (u16*)(ws + WS_TCWHI);
    u16* tcw_lo  = (u16*)(ws + WS_TCWLO);
    u16* feat_hi = (u16*)(ws + WS_FEATHI);
    u16* feat_lo = (u16*)(ws + WS_FEATLO);
    u16* wt_hi   = (u16*)(ws + WS_WTHI);
    u16* wt_lo   = (u16*)(ws + WS_WTLO);

    hipMemsetAsync(scal, 0, 256, stream);

    tcw_convert_kernel<<<dim3((NC * DIMM) / 256), 256, 0, stream>>>(
        code_weight, code_weight_bias, tcw_hi, tcw_lo);
    feat_convert_kernel<<<dim3((B_ * K1_) / 256), 256, 0, stream>>>(
        features, feat_hi, feat_lo);
    wt_convert_kernel<<<dim3(N1P / 32, K1_ / 32), 256, 0, stream>>>(
        final_W, wt_hi, wt_lo);
    gemm1_mfma_kernel<<<dim3(N1P / 128, B_ / 64), 256, 0, stream>>>(
        feat_hi, feat_lo, wt_hi, wt_lo, final_b, fa_hi, fa_lo);
    fill_ones_kernel<<<dim3(M_ / 256), 256, 0, stream>>>(fa_hi, fa_lo);
    gemm2_kernel<<<dim3(64, 64), 256, 0, stream>>>(fa_hi, fa_lo, tcw_hi, tcw_lo,
                                                   sparse_defaults, logits, scal);
    corr_kernel<<<dim3(NNZ_ / 256), 256, 0, stream>>>(sparse_rows, sparse_cols, sparse_values,
                                                      sparse_defaults, logits, corrpart);
    event_kernel<<<dim3(512), 256, 0, stream>>>(event_indices, fa_hi, fa_lo,
                                                tcw_hi, tcw_lo, evpart);
    final_kernel<<<dim3(1), 256, 0, stream>>>(mask, scal, evpart, corrpart, out);
}